// Round 1
// baseline (554.237 us; speedup 1.0000x reference)
//
#include <hip/hip_runtime.h>

// Problem constants (from reference setup_inputs)
#define Bn 4
#define Cn 128
#define Hn 192
#define Wn 640
#define Dn 96
#define HW (Hn * Wn)

// Tile geometry: 64 x-cols per block, 16 per wave; R u-window = [x0-96, x0+64) = 160 cols.
// LDS staging TRANSPOSED [u][c] bf16, pitch 40 halfwords (80 B):
//   - MFMA fragment (8 contiguous k per lane) = ONE ds_read_b128 at [u][8q].
//   - bank index per b128 = (20*u + 4*q) % 32 = 4*((5u+q) mod 8): bijective spread,
//     every bank serves exactly 32 B per 64-lane instruction -> byte-floor, conflict-free.
//   - staging writes: lane = u, wave w owns channels 8w..8w+7 -> one ds_write_b128/slot,
//     same (20*l) bank spread -> conflict-free.
#define PRh 40  // R pitch, halfwords
#define PLh 40  // L pitch, halfwords
#define EP 68   // epilogue pitch (floats): scatter = 2-way (free), b128 reads = uniform 8/bank floor

typedef float f32x4 __attribute__((ext_vector_type(4)));
typedef short short8 __attribute__((ext_vector_type(8)));
typedef unsigned short ushort8 __attribute__((ext_vector_type(8)));

__device__ __forceinline__ unsigned short f2bf(float f) {
  // fp32 -> bf16 round-to-nearest-even
  unsigned int u = __builtin_bit_cast(unsigned int, f);
  u += 0x7FFFu + ((u >> 16) & 1u);
  return (unsigned short)(u >> 16);
}

union SMem {
  struct {
    unsigned short R[160 * PRh];  // 12800 B  bf16 [u][c], u in [0,160)
    unsigned short L[64 * PLh];   //  5120 B  bf16 [x][c], x in [0,64)
  } s;                            // 17920 B
  float epi[48 * EP];             // 13056 B  -> union = 17920 B
};

__global__ __launch_bounds__(256, 5) void cost_volume_kernel(
    const float* __restrict__ left, const float* __restrict__ right,
    float* __restrict__ out) {
  __shared__ SMem sm;

  const int x0 = blockIdx.x * 64;        // 10 slabs, x fastest for R-overlap L2 locality
  const int y  = blockIdx.y;
  const int b  = blockIdx.z;
  const int t  = threadIdx.x;
  const int w  = t >> 6;                 // wave: x-tile [16w,16w+16) for MFMA, channel group 8w..8w+7 for staging
  const int l  = t & 63;                 // lane: u-column for staging
  const int n  = t & 15;                 // MFMA m/n index
  const int q  = (t >> 4) & 3;           // MFMA quad (k-subgroup 8q..8q+7)

  // acc[jj]: u-tile jj covers u_loc in [16w+16jj, +16); d = 96 + n - 16jj - (4q+r)
  f32x4 acc[7];
#pragma unroll
  for (int jj = 0; jj < 7; ++jj) acc[jj] = (f32x4){0.f, 0.f, 0.f, 0.f};

  const float* lrow = left  + ((size_t)(b * Cn) * Hn + y) * Wn + x0;
  const float* rrow = right + ((size_t)(b * Cn) * Hn + y) * Wn + x0 - 96;

  // Load-transposed staging: wave w loads channels ck+8w..ck+8w+7, lane l = u-column.
  // Each global_load_dword is 64 consecutive floats of one channel row (256 B, coalesced).
  float rv[3][8];  // R: u = l + 64*i, i=0..2 (i=2 half-masked, u<160)
  float lv[8];     // L: u = l
  auto load_chunk = [&](int ck) {
    const float* rb = rrow + (size_t)(ck + 8 * w) * HW;
#pragma unroll
    for (int i = 0; i < 3; ++i) {
      const int u = l + 64 * i;
      const bool ok = (u < 160) && (x0 + u >= 96);  // zero-fill x-d < 0
#pragma unroll
      for (int j = 0; j < 8; ++j) rv[i][j] = ok ? rb[(size_t)j * HW + u] : 0.f;
    }
    const float* lb = lrow + (size_t)(ck + 8 * w) * HW;
#pragma unroll
    for (int j = 0; j < 8; ++j) lv[j] = lb[(size_t)j * HW + l];
  };

  load_chunk(0);
#pragma unroll
  for (int kk = 0; kk < 4; ++kk) {
    __syncthreads();                     // prior chunk's fragment reads complete
    // convert + transpose-write: one b128 per row-slot, [u][8w..8w+7]
#pragma unroll
    for (int i = 0; i < 3; ++i) {
      const int u = l + 64 * i;
      if (u < 160) {
        ushort8 pk;
#pragma unroll
        for (int j = 0; j < 8; ++j) pk[j] = f2bf(rv[i][j]);
        *(ushort8*)&sm.s.R[u * PRh + 8 * w] = pk;
      }
    }
    {
      ushort8 pl;
#pragma unroll
      for (int j = 0; j < 8; ++j) pl[j] = f2bf(lv[j]);
      *(ushort8*)&sm.s.L[l * PLh + 8 * w] = pl;
    }
    __syncthreads();
    if (kk < 3) load_chunk(32 * (kk + 1));  // prefetch next chunk over the MFMA phase

    // fragments: lane (q,n) reads 8 contiguous bf16 (k = 8q..8q+7) -> ds_read_b128
    {
      const short8 bf = *(const short8*)&sm.s.L[(16 * w + n) * PLh + 8 * q];
#pragma unroll
      for (int jj = 0; jj < 7; ++jj) {
        const short8 af =
            *(const short8*)&sm.s.R[(16 * w + 16 * jj + n) * PRh + 8 * q];
        acc[jj] = __builtin_amdgcn_mfma_f32_16x16x32_bf16(af, bf, acc[jj], 0, 0, 0);
      }
    }
  }

  // ---- epilogue, two d-passes of 48 (keeps LDS union at 17.9 KB)
  // C/D layout: col = n (x), row = 4q + r (u); d = 96 + n - 16jj - 4q - r.
#pragma unroll
  for (int p = 0; p < 2; ++p) {
    __syncthreads();                     // staging reads / prior pass stores complete
#pragma unroll
    for (int jj = 0; jj < 7; ++jj)
#pragma unroll
      for (int r = 0; r < 4; ++r) {
        const int d = 96 + n - 16 * jj - 4 * q - r - 48 * p;
        if (d >= 0 && d < 48) sm.epi[d * EP + 16 * w + n] = acc[jj][r];
      }
    __syncthreads();
    const size_t obase = (((size_t)b * Dn + 48 * p) * Hn + y) * Wn + x0;
    const int tx = (t & 15) << 2;
    const int d0 = t >> 4;
#pragma unroll
    for (int ii = 0; ii < 3; ++ii) {     // 48 rows x 16 float4, coalesced
      const int d = d0 + 16 * ii;
      f32x4 v = *(const f32x4*)&sm.epi[d * EP + tx];
      *(f32x4*)&out[obase + (size_t)d * HW + tx] = v;
    }
  }
}

extern "C" void kernel_launch(void* const* d_in, const int* in_sizes, int n_in,
                              void* d_out, int out_size, void* d_ws, size_t ws_size,
                              hipStream_t stream) {
  const float* left  = (const float*)d_in[0];
  const float* right = (const float*)d_in[1];
  // d_in[2] = num_disparities (96) — fixed by problem constants above.
  float* out = (float*)d_out;
  dim3 grid(Wn / 64, Hn, Bn);  // (10, 192, 4), x fastest
  cost_volume_kernel<<<grid, dim3(256, 1, 1), 0, stream>>>(left, right, out);
}

// Round 2
// 546.645 us; speedup vs baseline: 1.0139x; 1.0139x over previous
//
#include <hip/hip_runtime.h>

// Problem constants (from reference setup_inputs)
#define Bn 4
#define Cn 128
#define Hn 192
#define Wn 640
#define Dn 96
#define HW (Hn * Wn)

// Tile geometry: 64 x-cols per block, 16 per wave; R u-window = [x0-96, x0+64) = 160 cols.
// LDS staging TRANSPOSED [u][c] bf16, pitch 40 halfwords (80 B):
//   - MFMA fragment (8 contiguous k per lane) = ONE ds_read_b128 at [u][8q].
//   - start bank = 4*((5u+q) mod 8): bijective spread, byte-floor, no stall conflicts.
//   - staging writes: lane = u, wave w owns channels 8w..8w+7 -> one ds_write_b128/slot.
#define PRh 40  // R pitch, halfwords
#define PLh 40  // L pitch, halfwords
#define EP 68   // epilogue pitch (floats): scatter = 2-way (free), b128 reads = 8/bank floor

typedef float f32x4 __attribute__((ext_vector_type(4)));
typedef short short8 __attribute__((ext_vector_type(8)));
typedef unsigned short ushort8 __attribute__((ext_vector_type(8)));

__device__ __forceinline__ unsigned short f2bf(float f) {
  // fp32 -> bf16 round-to-nearest-even
  unsigned int u = __builtin_bit_cast(unsigned int, f);
  u += 0x7FFFu + ((u >> 16) & 1u);
  return (unsigned short)(u >> 16);
}

union SMem {
  struct {
    unsigned short R[160 * PRh];  // 12800 B  bf16 [u][c], u in [0,160)
    unsigned short L[64 * PLh];   //  5120 B  bf16 [x][c], x in [0,64)
  } s;                            // 17920 B
  float epi[96 * EP];             // 26112 B  single-pass epilogue -> union 26112 B
};

// Raw barrier discipline (T3/T4): no vmcnt drain in the main loop. lgkmcnt(0)
// guarantees (a) ds_writes visible before readers cross, (b) frag ds_reads
// retired before the next chunk's writes (WAR on the single LDS buffer).
// sched_barrier(0) fences hoisting across the inline asm (rule #18).
#define LGKM0() asm volatile("s_waitcnt lgkmcnt(0)" ::: "memory")
#define SBAR()                         \
  do {                                 \
    __builtin_amdgcn_sched_barrier(0); \
    __builtin_amdgcn_s_barrier();      \
    __builtin_amdgcn_sched_barrier(0); \
  } while (0)

__global__ __launch_bounds__(256, 4) void cost_volume_kernel(
    const float* __restrict__ left, const float* __restrict__ right,
    float* __restrict__ out) {
  __shared__ SMem sm;

  // T1: XCD-chunked bijective swizzle (7680 % 8 == 0). Each XCD gets 960
  // consecutive flat ids (= 96 y-rows of one b): the 2.5x R-window overlap
  // between x-neighbors resolves in that XCD's L2.
  const int orig = blockIdx.x + 10 * (blockIdx.y + 192 * blockIdx.z);
  const int swz  = (orig & 7) * 960 + (orig >> 3);
  const int x0 = (swz % 10) * 64;
  const int yb = swz / 10;
  const int y  = yb % 192;
  const int b  = yb / 192;

  const int t = threadIdx.x;
  const int w = t >> 6;   // wave: x-tile [16w,16w+16) for MFMA, channels 8w..8w+7 for staging
  const int l = t & 63;   // lane: u-column for staging
  const int n = t & 15;   // MFMA m/n index
  const int q = (t >> 4) & 3;  // MFMA quad (k-subgroup 8q..8q+7)

  // acc[jj]: u-tile jj covers u_loc in [16w+16jj, +16); d = 96 + n - 16jj - (4q+r)
  f32x4 acc[7];
#pragma unroll
  for (int jj = 0; jj < 7; ++jj) acc[jj] = (f32x4){0.f, 0.f, 0.f, 0.f};

  const float* lrow = left  + ((size_t)(b * Cn) * Hn + y) * Wn + x0;
  const float* rrow = right + ((size_t)(b * Cn) * Hn + y) * Wn + x0 - 96;

  // 2-deep register prefetch: two chunk buffers (32 floats each).
  float ra[24], la[8], rb[24], lb[8];

  auto load_chunk = [&](float (&rv)[24], float (&lv)[8], int ck) {
    const float* rbp = rrow + (size_t)(ck + 8 * w) * HW;
#pragma unroll
    for (int i = 0; i < 3; ++i) {
      const int u = l + 64 * i;
      const bool ok = (u < 160) && (x0 + u >= 96);  // zero-fill x-d < 0
#pragma unroll
      for (int j = 0; j < 8; ++j) rv[i * 8 + j] = ok ? rbp[(size_t)j * HW + u] : 0.f;
    }
    const float* lbp = lrow + (size_t)(ck + 8 * w) * HW;
#pragma unroll
    for (int j = 0; j < 8; ++j) lv[j] = lbp[(size_t)j * HW + l];
  };

  auto store_chunk = [&](float (&rv)[24], float (&lv)[8]) {
    // compiler emits counted vmcnt here (only this buffer's 32 loads)
#pragma unroll
    for (int i = 0; i < 3; ++i) {
      const int u = l + 64 * i;
      if (u < 160) {
        ushort8 pk;
#pragma unroll
        for (int j = 0; j < 8; ++j) pk[j] = f2bf(rv[i * 8 + j]);
        *(ushort8*)&sm.s.R[u * PRh + 8 * w] = pk;
      }
    }
    ushort8 pl;
#pragma unroll
    for (int j = 0; j < 8; ++j) pl[j] = f2bf(lv[j]);
    *(ushort8*)&sm.s.L[l * PLh + 8 * w] = pl;
  };

  auto mfma_phase = [&]() {
    const short8 bf = *(const short8*)&sm.s.L[(16 * w + n) * PLh + 8 * q];
#pragma unroll
    for (int jj = 0; jj < 7; ++jj) {
      const short8 af =
          *(const short8*)&sm.s.R[(16 * w + 16 * jj + n) * PRh + 8 * q];
      acc[jj] = __builtin_amdgcn_mfma_f32_16x16x32_bf16(af, bf, acc[jj], 0, 0, 0);
    }
  };

  // ---- software-pipelined main loop: loads stay in flight across barriers.
  load_chunk(ra, la, 0);
  load_chunk(rb, lb, 32);

  // kk=0
  store_chunk(ra, la);       // waits c0 only (vmcnt 32: c1 stays in flight)
  load_chunk(ra, la, 64);    // issue c2 (regs just freed by the ds_writes)
  LGKM0(); SBAR();           // writes visible
  mfma_phase();
  LGKM0(); SBAR();           // frag reads retired before c1's writes
  // kk=1
  store_chunk(rb, lb);
  load_chunk(rb, lb, 96);    // issue c3
  LGKM0(); SBAR();
  mfma_phase();
  LGKM0(); SBAR();
  // kk=2
  store_chunk(ra, la);       // waits c2 (c3 stays in flight)
  LGKM0(); SBAR();
  mfma_phase();
  LGKM0(); SBAR();
  // kk=3
  store_chunk(rb, lb);
  LGKM0(); SBAR();
  mfma_phase();

  // ---- single-pass epilogue (LDS union 26.1 KB).
  // C/D layout: col = n (x), row = 4q + r (u); d = 96 + n - 16jj - 4q - r.
  __syncthreads();  // full drain: all frag reads done before union overwrite
#pragma unroll
  for (int jj = 0; jj < 7; ++jj)
#pragma unroll
    for (int r = 0; r < 4; ++r) {
      const int d = 96 + n - 16 * jj - 4 * q - r;
      if (d >= 0 && d < 96) sm.epi[d * EP + 16 * w + n] = acc[jj][r];
    }
  __syncthreads();
  const size_t obase = ((size_t)b * Dn * Hn + y) * (size_t)Wn + x0;
  const int tx = (t & 15) << 2;
  const int d0 = t >> 4;
#pragma unroll
  for (int ii = 0; ii < 6; ++ii) {  // 96 rows x 16 float4, coalesced
    const int d = d0 + 16 * ii;
    f32x4 v = *(const f32x4*)&sm.epi[d * EP + tx];
    *(f32x4*)&out[obase + (size_t)d * HW + tx] = v;
  }
}

extern "C" void kernel_launch(void* const* d_in, const int* in_sizes, int n_in,
                              void* d_out, int out_size, void* d_ws, size_t ws_size,
                              hipStream_t stream) {
  const float* left  = (const float*)d_in[0];
  const float* right = (const float*)d_in[1];
  // d_in[2] = num_disparities (96) — fixed by problem constants above.
  float* out = (float*)d_out;
  dim3 grid(Wn / 64, Hn, Bn);  // (10, 192, 4) -> 7680 blocks, swizzled in-kernel
  cost_volume_kernel<<<grid, dim3(256, 1, 1), 0, stream>>>(left, right, out);
}